// Round 4
// baseline (129.470 us; speedup 1.0000x reference)
//
#include <hip/hip_runtime.h>
#include <math.h>

// MaxPool2d: N=32, C=64, H=W=224, kernel=3, stride=2, padding=1 (-inf pad)
// Output: 32 x 64 x 112 x 112 (f32)
//
// Each thread computes an 8-row x 4-col output tile.
//   cols: group g covers output cols [4g, 4g+3]  -> input cols [8g-1, 8g+7]
//         (two aligned 16B loads + one scalar left element per row)
//   rows: tile t covers output rows [8t, 8t+7]   -> input rows [16t-1, 16t+15]
//         (17 rows per 16 unique -> 1.0625x read redundancy; overlap rows
//          folded into both adjacent output-row accumulators in regs)
// Left edge (g==0) substitutes -inf for col -1; top tile (t==0) skips row -1.
// Right/bottom never touch padding (2*111+1 = 223 = last valid index).

#define IH 224
#define IW 224
#define OH 112
#define OW 112
#define OW_GROUPS 28   // 112 / 4 output cols per thread
#define OH_TILES  14   // 112 / 8 output rows per thread

typedef float f32x4 __attribute__((ext_vector_type(4)));

__global__ void maxpool2d_k3s2p1_kernel(const float* __restrict__ in,
                                        float* __restrict__ out,
                                        int total_tiles) {
    int idx = blockIdx.x * blockDim.x + threadIdx.x;
    if (idx >= total_tiles) return;

    int g    = idx % OW_GROUPS;          // horizontal group of 4 output cols
    int rest = idx / OW_GROUPS;
    int t    = rest % OH_TILES;          // vertical tile of 8 output rows
    int nc   = rest / OH_TILES;          // fused N*C plane index

    const float* base = in + (size_t)nc * (IH * IW);
    const int iw0     = g * 8;           // first input col of the aligned span
    const int ihbase  = t * 16;          // input row for s=0

    float m[8][4];
    #pragma unroll
    for (int lo = 0; lo < 8; ++lo)
        #pragma unroll
        for (int j = 0; j < 4; ++j)
            m[lo][j] = -INFINITY;

    #pragma unroll
    for (int s = -1; s <= 15; ++s) {
        int ih = ihbase + s;
        if (s == -1 && ih < 0) continue;   // top padding row (t==0 only)

        const float* rp = base + (size_t)ih * IW + iw0;
        f32x4 a = *reinterpret_cast<const f32x4*>(rp);
        f32x4 b = *reinterpret_cast<const f32x4*>(rp + 4);
        float left = (g == 0) ? -INFINITY : rp[-1];

        // horizontal window maxes (windows rel. to iw0: [-1,0,1],[1,2,3],[3,4,5],[5,6,7])
        float h0 = fmaxf(left, fmaxf(a.x, a.y));
        float h1 = fmaxf(a.y,  fmaxf(a.z, a.w));
        float h2 = fmaxf(a.w,  fmaxf(b.x, b.y));
        float h3 = fmaxf(b.y,  fmaxf(b.z, b.w));

        // fold into the output rows this input row covers: |s - 2*lo| <= 1
        #pragma unroll
        for (int lo = 0; lo < 8; ++lo) {
            if (s >= 2 * lo - 1 && s <= 2 * lo + 1) {
                m[lo][0] = fmaxf(m[lo][0], h0);
                m[lo][1] = fmaxf(m[lo][1], h1);
                m[lo][2] = fmaxf(m[lo][2], h2);
                m[lo][3] = fmaxf(m[lo][3], h3);
            }
        }
    }

    #pragma unroll
    for (int lo = 0; lo < 8; ++lo) {
        int oh = t * 8 + lo;
        f32x4 o;
        o.x = m[lo][0]; o.y = m[lo][1]; o.z = m[lo][2]; o.w = m[lo][3];
        float* op = out + ((size_t)(nc * OH + oh) * OW) + g * 4;
        __builtin_nontemporal_store(o, reinterpret_cast<f32x4*>(op));
    }
}

extern "C" void kernel_launch(void* const* d_in, const int* in_sizes, int n_in,
                              void* d_out, int out_size, void* d_ws, size_t ws_size,
                              hipStream_t stream) {
    (void)in_sizes; (void)n_in; (void)d_ws; (void)ws_size; (void)out_size;
    const float* x = (const float*)d_in[0];
    float* out = (float*)d_out;

    const int NC = 32 * 64;
    const int total_tiles = NC * OH_TILES * OW_GROUPS;   // 802,816
    const int block = 256;
    const int grid = (total_tiles + block - 1) / block;

    maxpool2d_k3s2p1_kernel<<<grid, block, 0, stream>>>(x, out, total_tiles);
}

// Round 6
// 94.423 us; speedup vs baseline: 1.3712x; 1.3712x over previous
//
#include <hip/hip_runtime.h>
#include <math.h>

// MaxPool2d: N=32, C=64, H=W=224, kernel=3, stride=2, padding=1 (-inf pad)
// Output: 32 x 64 x 112 x 112 (f32)
//
// Block-level LDS staging to bound read redundancy at 33/32 = 1.031x:
//   Each block handles one (n,c) plane band: 16 output rows x 112 cols.
//   It stages input rows [32*band-1, 32*band+31] (33 rows x 224 cols,
//   28.9 KB LDS) with fully coalesced float4 loads (row -1 -> -inf fill),
//   then 224 of 256 threads each compute 2 output rows x 4 cols from LDS.
// Per output row: 3 LDS rows, each read as 2x ds_read_b128 + 1 scalar
// (left neighbor; -inf at the left edge = padding semantics).
// Bottom/right never touch padding (2*111+1 = 223 = last valid index).

#define IH 224
#define IW 224
#define OH 112
#define OW 112
#define BAND_OUT 16            // output rows per block
#define BAND_IN  33            // staged input rows (32 + 1 overlap)
#define NBANDS   7             // 112 / 16
#define VEC_PER_ROW 56         // 224 / 4 float4 per input row
#define STAGE_VECS (BAND_IN * VEC_PER_ROW)   // 1848

typedef float f32x4 __attribute__((ext_vector_type(4)));

__global__ void maxpool2d_k3s2p1_kernel(const float* __restrict__ in,
                                        float* __restrict__ out) {
    __shared__ __align__(16) float smem[BAND_IN * IW];   // 33 x 224 floats

    const int band = blockIdx.x % NBANDS;
    const int nc   = blockIdx.x / NBANDS;
    const int tid  = threadIdx.x;

    const float* base = in + (size_t)nc * (IH * IW);
    const int gi0 = 32 * band - 1;       // global input row of local row 0

    // ---- stage 33 x 224 floats, coalesced float4 ----
    #pragma unroll
    for (int i = tid; i < STAGE_VECS; i += 256) {
        int li = i / VEC_PER_ROW;        // local row 0..32
        int ci = i % VEC_PER_ROW;        // float4 index within row
        int gi = gi0 + li;
        f32x4 v;
        if (gi >= 0) {
            v = *reinterpret_cast<const f32x4*>(base + (size_t)gi * IW + ci * 4);
        } else {
            v.x = v.y = v.z = v.w = -INFINITY;   // top -inf padding row
        }
        *reinterpret_cast<f32x4*>(&smem[li * IW + ci * 4]) = v;
    }

    __syncthreads();

    // ---- compute: 224 threads, each 2 output rows x 4 output cols ----
    if (tid < 224) {
        const int g  = tid % 28;         // col group: output cols 4g..4g+3
        const int rr = tid / 28;         // row pair 0..7

        #pragma unroll
        for (int q = 0; q < 2; ++q) {
            const int ro = 2 * rr + q;   // local output row 0..15
            float m0 = -INFINITY, m1 = -INFINITY, m2 = -INFINITY, m3 = -INFINITY;

            #pragma unroll
            for (int k = 0; k < 3; ++k) {
                const int li = 2 * ro + k;           // local input row
                const float* rp = &smem[li * IW + g * 8];
                f32x4 a = *reinterpret_cast<const f32x4*>(rp);
                f32x4 b = *reinterpret_cast<const f32x4*>(rp + 4);
                float left = (g == 0) ? -INFINITY : rp[-1];

                // windows rel. to 8g: [-1,0,1],[1,2,3],[3,4,5],[5,6,7]
                m0 = fmaxf(m0, fmaxf(left, fmaxf(a.x, a.y)));
                m1 = fmaxf(m1, fmaxf(a.y,  fmaxf(a.z, a.w)));
                m2 = fmaxf(m2, fmaxf(a.w,  fmaxf(b.x, b.y)));
                m3 = fmaxf(m3, fmaxf(b.y,  fmaxf(b.z, b.w)));
            }

            const int oh = band * BAND_OUT + ro;
            f32x4 o;
            o.x = m0; o.y = m1; o.z = m2; o.w = m3;
            float* op = out + ((size_t)(nc * OH + oh) * OW) + g * 4;
            __builtin_nontemporal_store(o, reinterpret_cast<f32x4*>(op));
        }
    }
}

extern "C" void kernel_launch(void* const* d_in, const int* in_sizes, int n_in,
                              void* d_out, int out_size, void* d_ws, size_t ws_size,
                              hipStream_t stream) {
    (void)in_sizes; (void)n_in; (void)d_ws; (void)ws_size; (void)out_size;
    const float* x = (const float*)d_in[0];
    float* out = (float*)d_out;

    const int NC = 32 * 64;
    const int grid = NC * NBANDS;        // 14336 blocks
    maxpool2d_k3s2p1_kernel<<<grid, 256, 0, stream>>>(x, out);
}

// Round 7
// 93.094 us; speedup vs baseline: 1.3907x; 1.0143x over previous
//
#include <hip/hip_runtime.h>
#include <math.h>

// MaxPool2d: N=32, C=64, H=W=224, kernel=3, stride=2, padding=1 (-inf pad)
// Output: 32 x 64 x 112 x 112 (f32)
//
// R3 structure (88.7us, best so far) + chunked XCD-aware block swizzle.
//
// Each thread computes a 4-row x 4-col output tile.
//   cols: group g covers output cols [4g, 4g+3]  -> input cols [8g-1, 8g+7]
//         (two aligned 16B loads + one scalar left element per row)
//   rows: tile t covers output rows [4t, 4t+3]   -> input rows [8t-1, 8t+7]
//         (1.125x nominal read redundancy; overlap rows folded in regs)
// XCD swizzle: MI355X dispatches blocks round-robin across 8 XCDs with
// non-coherent L2s. Vertically adjacent tiles that straddle a block boundary
// share a boundary input row; chunked remap (XCD gets a contiguous block
// range; bijective since nblocks % 8 == 0) keeps consecutive blocks on one
// XCD so the shared row L2-hits instead of refetching from HBM.

#define IH 224
#define IW 224
#define OH 112
#define OW 112
#define OW_GROUPS 28   // 112 / 4 output cols per thread
#define OH_TILES  28   // 112 / 4 output rows per thread
#define NXCD 8

typedef float f32x4 __attribute__((ext_vector_type(4)));

__global__ void maxpool2d_k3s2p1_kernel(const float* __restrict__ in,
                                        float* __restrict__ out,
                                        int total_tiles, int blocks_per_xcd) {
    // chunked XCD swizzle: bid -> (bid % 8) * (nblocks/8) + bid / 8
    int bid = blockIdx.x;
    int swz = (bid % NXCD) * blocks_per_xcd + bid / NXCD;
    int idx = swz * blockDim.x + threadIdx.x;
    if (idx >= total_tiles) return;

    int g    = idx % OW_GROUPS;          // horizontal group of 4 output cols
    int rest = idx / OW_GROUPS;
    int t    = rest % OH_TILES;          // vertical tile of 4 output rows
    int nc   = rest / OH_TILES;          // fused N*C plane index

    const float* base = in + (size_t)nc * (IH * IW);
    const int iw0     = g * 8;           // first input col of the aligned span
    const int ihbase  = t * 8;           // input row for s=0

    float m[4][4];
    #pragma unroll
    for (int lo = 0; lo < 4; ++lo)
        #pragma unroll
        for (int j = 0; j < 4; ++j)
            m[lo][j] = -INFINITY;

    #pragma unroll
    for (int s = -1; s <= 7; ++s) {
        int ih = ihbase + s;
        if (s == -1 && ih < 0) continue;   // top padding row (t==0 only)

        const float* rp = base + (size_t)ih * IW + iw0;
        f32x4 a = *reinterpret_cast<const f32x4*>(rp);
        f32x4 b = *reinterpret_cast<const f32x4*>(rp + 4);
        float left = (g == 0) ? -INFINITY : rp[-1];

        // horizontal window maxes (windows rel. to iw0: [-1,0,1],[1,2,3],[3,4,5],[5,6,7])
        float h0 = fmaxf(left, fmaxf(a.x, a.y));
        float h1 = fmaxf(a.y,  fmaxf(a.z, a.w));
        float h2 = fmaxf(a.w,  fmaxf(b.x, b.y));
        float h3 = fmaxf(b.y,  fmaxf(b.z, b.w));

        // fold into the output rows this input row covers: |s - 2*lo| <= 1
        #pragma unroll
        for (int lo = 0; lo < 4; ++lo) {
            if (s >= 2 * lo - 1 && s <= 2 * lo + 1) {
                m[lo][0] = fmaxf(m[lo][0], h0);
                m[lo][1] = fmaxf(m[lo][1], h1);
                m[lo][2] = fmaxf(m[lo][2], h2);
                m[lo][3] = fmaxf(m[lo][3], h3);
            }
        }
    }

    #pragma unroll
    for (int lo = 0; lo < 4; ++lo) {
        int oh = t * 4 + lo;
        f32x4 o;
        o.x = m[lo][0]; o.y = m[lo][1]; o.z = m[lo][2]; o.w = m[lo][3];
        float* op = out + ((size_t)(nc * OH + oh) * OW) + g * 4;
        __builtin_nontemporal_store(o, reinterpret_cast<f32x4*>(op));
    }
}

extern "C" void kernel_launch(void* const* d_in, const int* in_sizes, int n_in,
                              void* d_out, int out_size, void* d_ws, size_t ws_size,
                              hipStream_t stream) {
    (void)in_sizes; (void)n_in; (void)d_ws; (void)ws_size; (void)out_size;
    const float* x = (const float*)d_in[0];
    float* out = (float*)d_out;

    const int NC = 32 * 64;
    const int total_tiles = NC * OH_TILES * OW_GROUPS;   // 1,605,632
    const int block = 256;
    const int grid = (total_tiles + block - 1) / block;  // 6272, % 8 == 0
    const int blocks_per_xcd = grid / NXCD;              // 784

    maxpool2d_k3s2p1_kernel<<<grid, block, 0, stream>>>(x, out, total_tiles,
                                                        blocks_per_xcd);
}

// Round 8
// 88.603 us; speedup vs baseline: 1.4612x; 1.0507x over previous
//
#include <hip/hip_runtime.h>
#include <math.h>

// MaxPool2d: N=32, C=64, H=W=224, kernel=3, stride=2, padding=1 (-inf pad)
// Output: 32 x 64 x 112 x 112 (f32)
//
// FINAL (R3 structure, 88.7us measured — best of 6 variants):
//  - Each thread computes a 4-row x 4-col output tile.
//      cols: group g covers output cols [4g, 4g+3]  -> input cols [8g-1, 8g+7]
//            (two aligned 16B loads + one scalar left element per row)
//      rows: tile t covers output rows [4t, 4t+3]   -> input rows [8t-1, 8t+7]
//  - Index order (g fastest, then t, then nc) makes a 256-thread block cover
//    ~9 vertically-adjacent tiles of one plane, so tile-boundary input rows
//    are intra-block cache hits: effective HBM read ~= unique 411 MB.
//    (Measured: LDS staging 94.4us, XCD swizzle 93.1us, 8-row tiles 129.5us
//     — all regressions; the simple form wins.)
//  - Left edge (g==0) substitutes -inf; top tile skips input row -1.
//    Right/bottom never touch padding (2*111+1 = 223 = last valid index).

#define IH 224
#define IW 224
#define OH 112
#define OW 112
#define OW_GROUPS 28   // 112 / 4 output cols per thread
#define OH_TILES  28   // 112 / 4 output rows per thread

typedef float f32x4 __attribute__((ext_vector_type(4)));

__global__ void maxpool2d_k3s2p1_kernel(const float* __restrict__ in,
                                        float* __restrict__ out,
                                        int total_tiles) {
    int idx = blockIdx.x * blockDim.x + threadIdx.x;
    if (idx >= total_tiles) return;

    int g    = idx % OW_GROUPS;          // horizontal group of 4 output cols
    int rest = idx / OW_GROUPS;
    int t    = rest % OH_TILES;          // vertical tile of 4 output rows
    int nc   = rest / OH_TILES;          // fused N*C plane index

    const float* base = in + (size_t)nc * (IH * IW);
    const int iw0     = g * 8;           // first input col of the aligned span
    const int ihbase  = t * 8;           // input row for s=0

    float m[4][4];
    #pragma unroll
    for (int lo = 0; lo < 4; ++lo)
        #pragma unroll
        for (int j = 0; j < 4; ++j)
            m[lo][j] = -INFINITY;

    #pragma unroll
    for (int s = -1; s <= 7; ++s) {
        int ih = ihbase + s;
        if (s == -1 && ih < 0) continue;   // top padding row (t==0 only)

        const float* rp = base + (size_t)ih * IW + iw0;
        f32x4 a = *reinterpret_cast<const f32x4*>(rp);
        f32x4 b = *reinterpret_cast<const f32x4*>(rp + 4);
        float left = (g == 0) ? -INFINITY : rp[-1];

        // horizontal window maxes (windows rel. to iw0: [-1,0,1],[1,2,3],[3,4,5],[5,6,7])
        float h0 = fmaxf(left, fmaxf(a.x, a.y));
        float h1 = fmaxf(a.y,  fmaxf(a.z, a.w));
        float h2 = fmaxf(a.w,  fmaxf(b.x, b.y));
        float h3 = fmaxf(b.y,  fmaxf(b.z, b.w));

        // fold into the output rows this input row covers: |s - 2*lo| <= 1
        #pragma unroll
        for (int lo = 0; lo < 4; ++lo) {
            if (s >= 2 * lo - 1 && s <= 2 * lo + 1) {
                m[lo][0] = fmaxf(m[lo][0], h0);
                m[lo][1] = fmaxf(m[lo][1], h1);
                m[lo][2] = fmaxf(m[lo][2], h2);
                m[lo][3] = fmaxf(m[lo][3], h3);
            }
        }
    }

    #pragma unroll
    for (int lo = 0; lo < 4; ++lo) {
        int oh = t * 4 + lo;
        f32x4 o;
        o.x = m[lo][0]; o.y = m[lo][1]; o.z = m[lo][2]; o.w = m[lo][3];
        float* op = out + ((size_t)(nc * OH + oh) * OW) + g * 4;
        __builtin_nontemporal_store(o, reinterpret_cast<f32x4*>(op));
    }
}

extern "C" void kernel_launch(void* const* d_in, const int* in_sizes, int n_in,
                              void* d_out, int out_size, void* d_ws, size_t ws_size,
                              hipStream_t stream) {
    (void)in_sizes; (void)n_in; (void)d_ws; (void)ws_size; (void)out_size;
    const float* x = (const float*)d_in[0];
    float* out = (float*)d_out;

    const int NC = 32 * 64;
    const int total_tiles = NC * OH_TILES * OW_GROUPS;   // 1,605,632
    const int block = 256;
    const int grid = (total_tiles + block - 1) / block;

    maxpool2d_k3s2p1_kernel<<<grid, block, 0, stream>>>(x, out, total_tiles);
}